// Round 10
// baseline (131.822 us; speedup 1.0000x reference)
//
#include <hip/hip_runtime.h>
#include <hip/hip_bf16.h>

typedef float f4 __attribute__((ext_vector_type(4)));
typedef float f2 __attribute__((ext_vector_type(2)));
typedef unsigned int u32;
typedef u32 u4 __attribute__((ext_vector_type(4)));

constexpr int B = 2, C = 16, D = 24, H = 48, W = 48;
constexpr int K = 27;
constexpr int SP = D * H * W;   // 55296 (divisible by 128)
constexpr int HW = H * W;

__device__ inline ushort bf16_bits(float f) {
    __hip_bfloat16 h = __float2bfloat16(f);   // RTN-E
    return __builtin_bit_cast(ushort, h);
}

// x [B,C,S] f32 -> xt [B,S,16ch] bf16 (32 B per spatial point)
__global__ __launch_bounds__(256) void xpose_bf16_kernel(const float* __restrict__ x,
                                                         u32* __restrict__ xt) {
    int t = blockIdx.x * blockDim.x + threadIdx.x;
    if (t >= B * SP) return;
    int s = t % SP, b = t / SP;
    const float* src = x + (size_t)b * C * SP + s;
    u4 pk[2];
#pragma unroll
    for (int m = 0; m < 8; ++m) {
        float lo = src[(size_t)(2 * m) * SP];
        float hi = src[(size_t)(2 * m + 1) * SP];
        pk[m >> 2][m & 3] = (u32)bf16_bits(lo) | ((u32)bf16_bits(hi) << 16);
    }
    u4* dst = reinterpret_cast<u4*>(xt + (size_t)t * 8);
    dst[0] = pk[0];
    dst[1] = pk[1];
}

// Thread = (k,p,q) handling BOTH b=0 and b=1: two independent gather chains
// in flight (16 dwordx4), shared prologue, one barrier, batched stores.
__global__ __launch_bounds__(256, 4) void deform_bf16_v10(const u32* __restrict__ xt,
                                                          const float* __restrict__ off,
                                                          float* __restrict__ out) {
    const int tid = blockIdx.x * blockDim.x + threadIdx.x;
    const int l = threadIdx.x & 63;
    const int q = l >> 5;                    // channel half 0/1
    const int c = l & 31;                    // sample-in-wave 0..31
    const int s = (tid >> 6) * 32 + c;       // (k,p) id, wave-uniform k
    const int p = s % SP;
    const int k = s / SP;                    // 0..26

    const int od = p / HW;
    const int rem = p - od * HW;
    const int oh = rem / W, ow = rem - oh * W;
    const int ki = k / 9, kr2 = k - ki * 9;
    const int kj = kr2 / 3, kk = kr2 - kj * 3;
    const float bd = (float)(od + ki - 1);
    const float bh = (float)(oh + kj - 1);
    const float bw = (float)(ow + kk - 1);

    // ---- offsets for both b, coalesced + shfl broadcast ----
    float offd[2], offh[2], offw[2];
#pragma unroll
    for (int b = 0; b < 2; ++b) {
        const size_t obase = ((size_t)b * (3 * K) + 3 * k) * SP;
        float vdh = __builtin_nontemporal_load(off + obase + (size_t)q * SP + p);
        float vw = 0.0f;
        if (l < 32) vw = __builtin_nontemporal_load(off + obase + (size_t)2 * SP + p);
        offd[b] = __shfl(vdh, c);
        offh[b] = __shfl(vdh, c + 32);
        offw[b] = __shfl(vw, c);
    }

    // ---- per-b indices, then ALL 16 gathers issued back-to-back ----
    u4 v[2][8];
    float fd[2], fh[2], fw[2];
    int d0_[2], h0_[2], w0_[2];
#pragma unroll
    for (int b = 0; b < 2; ++b) {
        float pd = bd + offd[b];
        float ph = bh + offh[b];
        float pw = bw + offw[b];
        float d0f = floorf(pd), h0f = floorf(ph), w0f = floorf(pw);
        fd[b] = pd - d0f; fh[b] = ph - h0f; fw[b] = pw - w0f;
        int d0 = (int)d0f, h0 = (int)h0f, w0 = (int)w0f;
        d0_[b] = d0; h0_[b] = h0; w0_[b] = w0;

        int dc0 = min(max(d0, 0), D - 1) * HW;
        int dc1 = min(max(d0 + 1, 0), D - 1) * HW;
        int hc0 = min(max(h0, 0), H - 1) * W;
        int hc1 = min(max(h0 + 1, 0), H - 1) * W;
        int wc0 = min(max(w0, 0), W - 1);
        int wc1 = min(max(w0 + 1, 0), W - 1);

        const u4* xb = reinterpret_cast<const u4*>(xt) + (size_t)b * SP * 2 + q;
#pragma unroll
        for (int cn = 0; cn < 8; ++cn) {
            int idx = ((cn & 4) ? dc1 : dc0) + ((cn & 2) ? hc1 : hc0) + ((cn & 1) ? wc1 : wc0);
            v[b][cn] = xb[(size_t)idx * 2];
        }
    }

    // ---- weights for both b (VALU overlaps in-flight loads) ----
    float wgt[2][8];
#pragma unroll
    for (int b = 0; b < 2; ++b) {
        int d0 = d0_[b], h0 = h0_[b], w0 = w0_[b];
        bool vd0 = (d0 >= 0) & (d0 < D), vd1 = (d0 + 1 >= 0) & (d0 + 1 < D);
        bool vh0 = (h0 >= 0) & (h0 < H), vh1 = (h0 + 1 >= 0) & (h0 + 1 < H);
        bool vw0 = (w0 >= 0) & (w0 < W), vw1 = (w0 + 1 >= 0) & (w0 + 1 < W);
        float wd0 = 1.0f - fd[b], wd1 = fd[b];
        float wh0 = 1.0f - fh[b], wh1 = fh[b];
        float ww0 = 1.0f - fw[b], ww1 = fw[b];
#pragma unroll
        for (int cn = 0; cn < 8; ++cn) {
            bool valid = ((cn & 4) ? vd1 : vd0) & ((cn & 2) ? vh1 : vh0) & ((cn & 1) ? vw1 : vw0);
            float wv2 = ((cn & 4) ? wd1 : wd0) * ((cn & 2) ? wh1 : wh0) * ((cn & 1) ? ww1 : ww0);
            wgt[b][cn] = valid ? wv2 : 0.0f;
        }
    }

    // ---- accumulate ----
    f2 acc[2][4] = {};
#pragma unroll
    for (int b = 0; b < 2; ++b) {
#pragma unroll
        for (int cn = 0; cn < 8; ++cn) {
            f2 w2 = {wgt[b][cn], wgt[b][cn]};
#pragma unroll
            for (int m = 0; m < 4; ++m) {
                u32 wb = v[b][cn][m];
                f2 xv = {__builtin_bit_cast(float, wb << 16),
                         __builtin_bit_cast(float, wb & 0xffff0000u)};
                acc[b][m] += w2 * xv;
            }
        }
    }

    // ---- wave-local transpose, double-buffered over b; ONE barrier ----
    __shared__ float tile[2][4][16][36];
    const int wv = threadIdx.x >> 6;
#pragma unroll
    for (int b = 0; b < 2; ++b)
#pragma unroll
        for (int m = 0; m < 4; ++m) {
            tile[b][wv][8 * q + 2 * m][c] = acc[b][m][0];
            tile[b][wv][8 * q + 2 * m + 1][c] = acc[b][m][1];
        }
    __syncthreads();

    const int p_base = p - c;                 // wave-uniform, 32-aligned
    const int ch_lo = l >> 3;                 // 0..7
    const int p0 = 4 * (l & 7);
#pragma unroll
    for (int b = 0; b < 2; ++b) {
        float* osb = out + ((size_t)b * C * K) * SP + p_base + p0;
#pragma unroll
        for (int rr = 0; rr < 2; ++rr) {
            int ch = 8 * rr + ch_lo;
            f4 vv = *reinterpret_cast<const f4*>(&tile[b][wv][ch][p0]);
            *reinterpret_cast<f4*>(osb + ((size_t)ch * K + k) * SP) = vv;
        }
    }
}

// fallback (no workspace): one thread per sample, gather from native fp32 layout
__global__ __launch_bounds__(256) void deform_kernel_nat(const float* __restrict__ x,
                                                         const float* __restrict__ off,
                                                         float* __restrict__ out) {
    int tid = blockIdx.x * blockDim.x + threadIdx.x;
    if (tid >= B * K * SP) return;
    int p = tid % SP;
    int bk = tid / SP;
    int k = bk % K, b = bk / K;

    const float* ob = off + ((size_t)b * (3 * K) + 3 * k) * SP + p;
    float offd = ob[0];
    float offh = ob[(size_t)SP];
    float offw = ob[(size_t)2 * SP];

    int od = p / HW, rem = p - od * HW;
    int oh = rem / W, ow = rem - oh * W;
    int ki = k / 9, kr = k - ki * 9;
    int kj = kr / 3, kk = kr - kj * 3;

    float pd = (float)(od + ki - 1) + offd;
    float ph = (float)(oh + kj - 1) + offh;
    float pw = (float)(ow + kk - 1) + offw;

    float d0f = floorf(pd), h0f = floorf(ph), w0f = floorf(pw);
    float fd = pd - d0f, fh = ph - h0f, fw = pw - w0f;
    int d0 = (int)d0f, h0 = (int)h0f, w0 = (int)w0f;

    f4 acc[4] = {};
#pragma unroll
    for (int ci = 0; ci < 2; ++ci) {
        int ds = d0 + ci;
        bool vd = (ds >= 0) & (ds < D);
        float wd = ci ? fd : 1.0f - fd;
        int dc = min(max(ds, 0), D - 1);
#pragma unroll
        for (int cj = 0; cj < 2; ++cj) {
            int hs = h0 + cj;
            bool vh = (hs >= 0) & (hs < H);
            float wh = cj ? fh : 1.0f - fh;
            int hc = min(max(hs, 0), H - 1);
#pragma unroll
            for (int ck = 0; ck < 2; ++ck) {
                int ws = w0 + ck;
                bool vw = (ws >= 0) & (ws < W);
                float ww = ck ? fw : 1.0f - fw;
                int wc = min(max(ws, 0), W - 1);
                float wgt = (vd & vh & vw) ? wd * wh * ww : 0.0f;
                int idx = (dc * H + hc) * W + wc;
                const float* src = x + (size_t)b * C * SP + idx;
#pragma unroll
                for (int c2 = 0; c2 < C; ++c2)
                    acc[c2 >> 2][c2 & 3] += wgt * src[(size_t)c2 * SP];
            }
        }
    }

    float* o = out + ((size_t)b * C * K + k) * SP + p;
#pragma unroll
    for (int c2 = 0; c2 < C; ++c2)
        o[(size_t)c2 * K * SP] = acc[c2 >> 2][c2 & 3];
}

extern "C" void kernel_launch(void* const* d_in, const int* in_sizes, int n_in,
                              void* d_out, int out_size, void* d_ws, size_t ws_size,
                              hipStream_t stream) {
    const float* x = (const float*)d_in[0];
    const float* off = (const float*)d_in[1];
    float* out = (float*)d_out;

    const size_t xt_bytes = (size_t)B * SP * 16 * sizeof(ushort);  // 3.5 MB

    if (ws_size >= xt_bytes) {
        u32* xt = (u32*)d_ws;
        const int n_x = B * SP;
        xpose_bf16_kernel<<<(n_x + 255) / 256, 256, 0, stream>>>(x, xt);
        const long long n_thr = (long long)K * SP * 2;       // 2,985,984
        const int grid = (int)(n_thr / 256);                 // 11664, exact
        deform_bf16_v10<<<grid, 256, 0, stream>>>(xt, off, out);
    } else {
        const int n_main = B * K * SP;
        deform_kernel_nat<<<(n_main + 255) / 256, 256, 0, stream>>>(x, off, out);
    }
}

// Round 11
// 119.573 us; speedup vs baseline: 1.1024x; 1.1024x over previous
//
#include <hip/hip_runtime.h>
#include <hip/hip_bf16.h>

typedef float f4 __attribute__((ext_vector_type(4)));
typedef float f2 __attribute__((ext_vector_type(2)));
typedef unsigned int u32;
typedef u32 u4 __attribute__((ext_vector_type(4)));

constexpr int B = 2, C = 16, D = 24, H = 48, W = 48;
constexpr int K = 27;
constexpr int SP = D * H * W;   // 55296 (divisible by 64)
constexpr int HW = H * W;

__device__ inline ushort bf16_bits(float f) {
    __hip_bfloat16 h = __float2bfloat16(f);   // RTN-E
    return __builtin_bit_cast(ushort, h);
}

// x [B,C,S] f32 -> xt [B,S,16ch] bf16 (32 B per spatial point)
__global__ __launch_bounds__(256) void xpose_bf16_kernel(const float* __restrict__ x,
                                                         u32* __restrict__ xt) {
    int t = blockIdx.x * blockDim.x + threadIdx.x;
    if (t >= B * SP) return;
    int s = t % SP, b = t / SP;
    const float* src = x + (size_t)b * C * SP + s;
    u4 pk[2];
#pragma unroll
    for (int m = 0; m < 8; ++m) {
        float lo = src[(size_t)(2 * m) * SP];
        float hi = src[(size_t)(2 * m + 1) * SP];
        pk[m >> 2][m & 3] = (u32)bf16_bits(lo) | ((u32)bf16_bits(hi) << 16);
    }
    u4* dst = reinterpret_cast<u4*>(xt + (size_t)t * 8);
    dst[0] = pk[0];
    dst[1] = pk[1];
}

// Wave = 64 consecutive p at fixed (b,k). Lane (q=l>>5, c=l&31) handles
// samples pA=p_base+c and pB=pA+32, channels 8q..8q+7 each.
// Two independent gather chains per thread; same neighborhood (no footprint 2x).
// XCD chunked swizzle: each XCD gets a contiguous range of blocks.
__global__ __launch_bounds__(256, 4) void deform_bf16_v11(const u32* __restrict__ xt,
                                                          const float* __restrict__ off,
                                                          float* __restrict__ out) {
    // bijective chunked swizzle (gridDim.x = 11664, divisible by 8)
    const int cpx = gridDim.x >> 3;
    const int sbid = (blockIdx.x & 7) * cpx + (blockIdx.x >> 3);
    const int tid = sbid * 256 + threadIdx.x;

    const int l = threadIdx.x & 63;
    const int q = l >> 5;                    // channel half 0/1
    const int c = l & 31;
    const int w = tid >> 6;                  // global wave id
    const int plane = (w * 64) / SP;         // wave-uniform (SP % 64 == 0)
    const int p_base = (w * 64) % SP;
    const int k = plane % K, b = plane / K;

    const int ki = k / 9, kr2 = k - ki * 9;
    const int kj = kr2 / 3, kk = kr2 - kj * 3;

    // ---- offsets: 3 fully-coalesced wave-wide loads + shfl broadcast ----
    const size_t obase = ((size_t)b * (3 * K) + 3 * k) * SP + p_base;
    float r0 = __builtin_nontemporal_load(off + obase + l);
    float r1 = __builtin_nontemporal_load(off + obase + (size_t)SP + l);
    float r2 = __builtin_nontemporal_load(off + obase + (size_t)2 * SP + l);

    const u4* xb = reinterpret_cast<const u4*>(xt) + (size_t)b * SP * 2 + q;

    u4 v[2][8];
    float wgt[2][8];
#pragma unroll
    for (int s2 = 0; s2 < 2; ++s2) {
        const int p = p_base + 32 * s2 + c;
        const float offd = __shfl(r0, 32 * s2 + c);
        const float offh = __shfl(r1, 32 * s2 + c);
        const float offw = __shfl(r2, 32 * s2 + c);

        const int od = p / HW;
        const int rem = p - od * HW;
        const int oh = rem / W, ow = rem - oh * W;

        float pd = (float)(od + ki - 1) + offd;
        float ph = (float)(oh + kj - 1) + offh;
        float pw = (float)(ow + kk - 1) + offw;

        float d0f = floorf(pd), h0f = floorf(ph), w0f = floorf(pw);
        float fd = pd - d0f, fh = ph - h0f, fw = pw - w0f;
        int d0 = (int)d0f, h0 = (int)h0f, w0 = (int)w0f;

        int dc0 = min(max(d0, 0), D - 1) * HW;
        int dc1 = min(max(d0 + 1, 0), D - 1) * HW;
        int hc0 = min(max(h0, 0), H - 1) * W;
        int hc1 = min(max(h0 + 1, 0), H - 1) * W;
        int wc0 = min(max(w0, 0), W - 1);
        int wc1 = min(max(w0 + 1, 0), W - 1);

        // issue all 8 gathers for this sample back-to-back
#pragma unroll
        for (int cn = 0; cn < 8; ++cn) {
            int idx = ((cn & 4) ? dc1 : dc0) + ((cn & 2) ? hc1 : hc0) + ((cn & 1) ? wc1 : wc0);
            v[s2][cn] = xb[(size_t)idx * 2];
        }

        bool vd0 = (d0 >= 0) & (d0 < D), vd1 = (d0 + 1 >= 0) & (d0 + 1 < D);
        bool vh0 = (h0 >= 0) & (h0 < H), vh1 = (h0 + 1 >= 0) & (h0 + 1 < H);
        bool vw0 = (w0 >= 0) & (w0 < W), vw1 = (w0 + 1 >= 0) & (w0 + 1 < W);
        float wd0 = 1.0f - fd, wd1 = fd;
        float wh0 = 1.0f - fh, wh1 = fh;
        float ww0 = 1.0f - fw, ww1 = fw;
#pragma unroll
        for (int cn = 0; cn < 8; ++cn) {
            bool valid = ((cn & 4) ? vd1 : vd0) & ((cn & 2) ? vh1 : vh0) & ((cn & 1) ? vw1 : vw0);
            float ww2 = ((cn & 4) ? wd1 : wd0) * ((cn & 2) ? wh1 : wh0) * ((cn & 1) ? ww1 : ww0);
            wgt[s2][cn] = valid ? ww2 : 0.0f;
        }
    }

    // ---- accumulate (both chains) ----
    f2 acc[2][4] = {};
#pragma unroll
    for (int s2 = 0; s2 < 2; ++s2)
#pragma unroll
        for (int cn = 0; cn < 8; ++cn) {
            f2 w2 = {wgt[s2][cn], wgt[s2][cn]};
#pragma unroll
            for (int m = 0; m < 4; ++m) {
                u32 wb = v[s2][cn][m];
                f2 xv = {__builtin_bit_cast(float, wb << 16),
                         __builtin_bit_cast(float, wb & 0xffff0000u)};
                acc[s2][m] += w2 * xv;
            }
        }

    // ---- wave-local transpose: [ch16][p64] tile; stores 4x dense 1KB insts ----
    __shared__ float tile[4][16][68];
    const int wv = threadIdx.x >> 6;
#pragma unroll
    for (int s2 = 0; s2 < 2; ++s2)
#pragma unroll
        for (int m = 0; m < 4; ++m) {
            tile[wv][8 * q + 2 * m][32 * s2 + c] = acc[s2][m][0];
            tile[wv][8 * q + 2 * m + 1][32 * s2 + c] = acc[s2][m][1];
        }
    __syncthreads();

    const int col = 4 * (l & 15);
    const int ch_base = l >> 4;              // 0..3
    float* osb = out + ((size_t)b * C * K) * SP + p_base + col;
#pragma unroll
    for (int j = 0; j < 4; ++j) {
        int ch = 4 * j + ch_base;
        f4 vv = *reinterpret_cast<const f4*>(&tile[wv][ch][col]);
        *reinterpret_cast<f4*>(osb + ((size_t)ch * K + k) * SP) = vv;
    }
}

// fallback (no workspace): one thread per sample, gather from native fp32 layout
__global__ __launch_bounds__(256) void deform_kernel_nat(const float* __restrict__ x,
                                                         const float* __restrict__ off,
                                                         float* __restrict__ out) {
    int tid = blockIdx.x * blockDim.x + threadIdx.x;
    if (tid >= B * K * SP) return;
    int p = tid % SP;
    int bk = tid / SP;
    int k = bk % K, b = bk / K;

    const float* ob = off + ((size_t)b * (3 * K) + 3 * k) * SP + p;
    float offd = ob[0];
    float offh = ob[(size_t)SP];
    float offw = ob[(size_t)2 * SP];

    int od = p / HW, rem = p - od * HW;
    int oh = rem / W, ow = rem - oh * W;
    int ki = k / 9, kr = k - ki * 9;
    int kj = kr / 3, kk = kr - kj * 3;

    float pd = (float)(od + ki - 1) + offd;
    float ph = (float)(oh + kj - 1) + offh;
    float pw = (float)(ow + kk - 1) + offw;

    float d0f = floorf(pd), h0f = floorf(ph), w0f = floorf(pw);
    float fd = pd - d0f, fh = ph - h0f, fw = pw - w0f;
    int d0 = (int)d0f, h0 = (int)h0f, w0 = (int)w0f;

    f4 acc[4] = {};
#pragma unroll
    for (int ci = 0; ci < 2; ++ci) {
        int ds = d0 + ci;
        bool vd = (ds >= 0) & (ds < D);
        float wd = ci ? fd : 1.0f - fd;
        int dc = min(max(ds, 0), D - 1);
#pragma unroll
        for (int cj = 0; cj < 2; ++cj) {
            int hs = h0 + cj;
            bool vh = (hs >= 0) & (hs < H);
            float wh = cj ? fh : 1.0f - fh;
            int hc = min(max(hs, 0), H - 1);
#pragma unroll
            for (int ck = 0; ck < 2; ++ck) {
                int ws = w0 + ck;
                bool vw = (ws >= 0) & (ws < W);
                float ww = ck ? fw : 1.0f - fw;
                int wc = min(max(ws, 0), W - 1);
                float wgt = (vd & vh & vw) ? wd * wh * ww : 0.0f;
                int idx = (dc * H + hc) * W + wc;
                const float* src = x + (size_t)b * C * SP + idx;
#pragma unroll
                for (int c2 = 0; c2 < C; ++c2)
                    acc[c2 >> 2][c2 & 3] += wgt * src[(size_t)c2 * SP];
            }
        }
    }

    float* o = out + ((size_t)b * C * K + k) * SP + p;
#pragma unroll
    for (int c2 = 0; c2 < C; ++c2)
        o[(size_t)c2 * K * SP] = acc[c2 >> 2][c2 & 3];
}

extern "C" void kernel_launch(void* const* d_in, const int* in_sizes, int n_in,
                              void* d_out, int out_size, void* d_ws, size_t ws_size,
                              hipStream_t stream) {
    const float* x = (const float*)d_in[0];
    const float* off = (const float*)d_in[1];
    float* out = (float*)d_out;

    const size_t xt_bytes = (size_t)B * SP * 16 * sizeof(ushort);  // 3.5 MB

    if (ws_size >= xt_bytes) {
        u32* xt = (u32*)d_ws;
        const int n_x = B * SP;
        xpose_bf16_kernel<<<(n_x + 255) / 256, 256, 0, stream>>>(x, xt);
        const long long n_thr = (long long)B * K * SP;       // 2,985,984 (2 samples/thread)
        const int grid = (int)(n_thr / 256);                 // 11664, exact, %8==0
        deform_bf16_v11<<<grid, 256, 0, stream>>>(xt, off, out);
    } else {
        const int n_main = B * K * SP;
        deform_kernel_nat<<<(n_main + 255) / 256, 256, 0, stream>>>(x, off, out);
    }
}

// Round 12
// 111.210 us; speedup vs baseline: 1.1853x; 1.0752x over previous
//
#include <hip/hip_runtime.h>
#include <hip/hip_bf16.h>

typedef float f4 __attribute__((ext_vector_type(4)));
typedef float f2 __attribute__((ext_vector_type(2)));
typedef unsigned int u32;
typedef u32 u4 __attribute__((ext_vector_type(4)));

constexpr int B = 2, C = 16, D = 24, H = 48, W = 48;
constexpr int K = 27;
constexpr int SP = D * H * W;   // 55296 (divisible by 128)
constexpr int HW = H * W;

__device__ inline ushort bf16_bits(float f) {
    __hip_bfloat16 h = __float2bfloat16(f);   // RTN-E
    return __builtin_bit_cast(ushort, h);
}

__device__ inline void gather16_to_lds(const void* g, void* l) {
    __builtin_amdgcn_global_load_lds(
        (const __attribute__((address_space(1))) u32*)g,
        (__attribute__((address_space(3))) u32*)l, 16, 0, 0);
}

// x [B,C,S] f32 -> xt [B,S,16ch] bf16 (32 B per spatial point)
__global__ __launch_bounds__(256) void xpose_bf16_kernel(const float* __restrict__ x,
                                                         u32* __restrict__ xt) {
    int t = blockIdx.x * blockDim.x + threadIdx.x;
    if (t >= B * SP) return;
    int s = t % SP, b = t / SP;
    const float* src = x + (size_t)b * C * SP + s;
    u4 pk[2];
#pragma unroll
    for (int m = 0; m < 8; ++m) {
        float lo = src[(size_t)(2 * m) * SP];
        float hi = src[(size_t)(2 * m + 1) * SP];
        pk[m >> 2][m & 3] = (u32)bf16_bits(lo) | ((u32)bf16_bits(hi) << 16);
    }
    u4* dst = reinterpret_cast<u4*>(xt + (size_t)t * 8);
    dst[0] = pk[0];
    dst[1] = pk[1];
}

// R9 mapping (wave = 32 samples x 2 channel-halves) with ASYNC gathers:
// 8 x global_load_lds (per-lane source addr = HW gather, zero data VGPRs,
// single vmcnt(0) wait) -> ds_read_b128 -> FMA -> aliased transpose tile.
__global__ __launch_bounds__(256, 4) void deform_bf16_v12(const u32* __restrict__ xt,
                                                          const float* __restrict__ off,
                                                          float* __restrict__ out) {
    const int tid = blockIdx.x * blockDim.x + threadIdx.x;
    const int l = threadIdx.x & 63;
    const int q = l >> 5;                    // channel half 0/1
    const int c = l & 31;                    // sample-in-wave 0..31
    const int s = (tid >> 6) * 32 + c;       // global sample id
    const int p = s % SP;
    const int bk = s / SP;                   // wave-uniform (SP % 32 == 0)
    const int k = bk % K, b = bk / K;

    __shared__ u4 stag[4][8][64];            // 32 KiB: [wave][corner][lane]
    const int wv = threadIdx.x >> 6;

    // offsets: 1 full-wave + 1 half-wave coalesced load, then shfl broadcast
    const size_t obase = ((size_t)b * (3 * K) + 3 * k) * SP;
    float vdh = __builtin_nontemporal_load(off + obase + (size_t)q * SP + p);
    float vw = 0.0f;
    if (l < 32) vw = __builtin_nontemporal_load(off + obase + (size_t)2 * SP + p);
    float offd = __shfl(vdh, c);
    float offh = __shfl(vdh, c + 32);
    float offw = __shfl(vw, c);

    const int od = p / HW;
    const int rem = p - od * HW;
    const int oh = rem / W, ow = rem - oh * W;
    const int ki = k / 9, kr2 = k - ki * 9;
    const int kj = kr2 / 3, kk = kr2 - kj * 3;

    float pd = (float)(od + ki - 1) + offd;
    float ph = (float)(oh + kj - 1) + offh;
    float pw = (float)(ow + kk - 1) + offw;

    float d0f = floorf(pd), h0f = floorf(ph), w0f = floorf(pw);
    float fd = pd - d0f, fh = ph - h0f, fw = pw - w0f;
    int d0 = (int)d0f, h0 = (int)h0f, w0 = (int)w0f;

    int dc0 = min(max(d0, 0), D - 1) * HW;
    int dc1 = min(max(d0 + 1, 0), D - 1) * HW;
    int hc0 = min(max(h0, 0), H - 1) * W;
    int hc1 = min(max(h0 + 1, 0), H - 1) * W;
    int wc0 = min(max(w0, 0), W - 1);
    int wc1 = min(max(w0 + 1, 0), W - 1);

    const u4* xb = reinterpret_cast<const u4*>(xt) + (size_t)b * SP * 2 + q;

    // ---- 8 async gathers, issued back-to-back, no data VGPRs ----
#pragma unroll
    for (int cn = 0; cn < 8; ++cn) {
        int idx = ((cn & 4) ? dc1 : dc0) + ((cn & 2) ? hc1 : hc0) + ((cn & 1) ? wc1 : wc0);
        gather16_to_lds(xb + (size_t)idx * 2, &stag[wv][cn][0]);
    }

    // ---- weights computed while DMAs are in flight ----
    bool vd0 = (d0 >= 0) & (d0 < D), vd1 = (d0 + 1 >= 0) & (d0 + 1 < D);
    bool vh0 = (h0 >= 0) & (h0 < H), vh1 = (h0 + 1 >= 0) & (h0 + 1 < H);
    bool vw0 = (w0 >= 0) & (w0 < W), vw1 = (w0 + 1 >= 0) & (w0 + 1 < W);
    float wd0 = 1.0f - fd, wd1 = fd;
    float wh0 = 1.0f - fh, wh1 = fh;
    float ww0 = 1.0f - fw, ww1 = fw;

    float wgt[8];
#pragma unroll
    for (int cn = 0; cn < 8; ++cn) {
        bool valid = ((cn & 4) ? vd1 : vd0) & ((cn & 2) ? vh1 : vh0) & ((cn & 1) ? vw1 : vw0);
        float wv2 = ((cn & 4) ? wd1 : wd0) * ((cn & 2) ? wh1 : wh0) * ((cn & 1) ? ww1 : ww0);
        wgt[cn] = valid ? wv2 : 0.0f;
    }

    // ---- single wait for all 8 gathers ----
    asm volatile("s_waitcnt vmcnt(0)" ::: "memory");
    __builtin_amdgcn_sched_barrier(0);

    // ---- read back own 16B slots (contiguous, conflict-free) + FMA ----
    f2 acc[4] = {};
#pragma unroll
    for (int cn = 0; cn < 8; ++cn) {
        u4 v = stag[wv][cn][l];
        f2 w2 = {wgt[cn], wgt[cn]};
#pragma unroll
        for (int m = 0; m < 4; ++m) {
            u32 wb = v[m];
            f2 xv = {__builtin_bit_cast(float, wb << 16),
                     __builtin_bit_cast(float, wb & 0xffff0000u)};
            acc[m] += w2 * xv;
        }
    }

    // ---- transpose tile aliased into this wave's (now dead) staging region ----
    float* tile = reinterpret_cast<float*>(&stag[wv][0][0]);   // [16][36] floats
#pragma unroll
    for (int m = 0; m < 4; ++m) {
        tile[(8 * q + 2 * m) * 36 + c] = acc[m][0];
        tile[(8 * q + 2 * m + 1) * 36 + c] = acc[m][1];
    }
    __syncthreads();

    const int p_base = p - c;                 // wave-uniform, 32-aligned
    const int ch_lo = l >> 3;                 // 0..7
    const int p0 = 4 * (l & 7);
    float* osb = out + ((size_t)b * C * K) * SP + p_base + p0;
#pragma unroll
    for (int rr = 0; rr < 2; ++rr) {
        int ch = 8 * rr + ch_lo;
        f4 vv = *reinterpret_cast<const f4*>(&tile[ch * 36 + p0]);
        *reinterpret_cast<f4*>(osb + ((size_t)ch * K + k) * SP) = vv;
    }
}

// fallback (no workspace): one thread per sample, gather from native fp32 layout
__global__ __launch_bounds__(256) void deform_kernel_nat(const float* __restrict__ x,
                                                         const float* __restrict__ off,
                                                         float* __restrict__ out) {
    int tid = blockIdx.x * blockDim.x + threadIdx.x;
    if (tid >= B * K * SP) return;
    int p = tid % SP;
    int bk = tid / SP;
    int k = bk % K, b = bk / K;

    const float* ob = off + ((size_t)b * (3 * K) + 3 * k) * SP + p;
    float offd = ob[0];
    float offh = ob[(size_t)SP];
    float offw = ob[(size_t)2 * SP];

    int od = p / HW, rem = p - od * HW;
    int oh = rem / W, ow = rem - oh * W;
    int ki = k / 9, kr = k - ki * 9;
    int kj = kr / 3, kk = kr - kj * 3;

    float pd = (float)(od + ki - 1) + offd;
    float ph = (float)(oh + kj - 1) + offh;
    float pw = (float)(ow + kk - 1) + offw;

    float d0f = floorf(pd), h0f = floorf(ph), w0f = floorf(pw);
    float fd = pd - d0f, fh = ph - h0f, fw = pw - w0f;
    int d0 = (int)d0f, h0 = (int)h0f, w0 = (int)w0f;

    f4 acc[4] = {};
#pragma unroll
    for (int ci = 0; ci < 2; ++ci) {
        int ds = d0 + ci;
        bool vd = (ds >= 0) & (ds < D);
        float wd = ci ? fd : 1.0f - fd;
        int dc = min(max(ds, 0), D - 1);
#pragma unroll
        for (int cj = 0; cj < 2; ++cj) {
            int hs = h0 + cj;
            bool vh = (hs >= 0) & (hs < H);
            float wh = cj ? fh : 1.0f - fh;
            int hc = min(max(hs, 0), H - 1);
#pragma unroll
            for (int ck = 0; ck < 2; ++ck) {
                int ws = w0 + ck;
                bool vw = (ws >= 0) & (ws < W);
                float ww = ck ? fw : 1.0f - fw;
                int wc = min(max(ws, 0), W - 1);
                float wgt = (vd & vh & vw) ? wd * wh * ww : 0.0f;
                int idx = (dc * H + hc) * W + wc;
                const float* src = x + (size_t)b * C * SP + idx;
#pragma unroll
                for (int c2 = 0; c2 < C; ++c2)
                    acc[c2 >> 2][c2 & 3] += wgt * src[(size_t)c2 * SP];
            }
        }
    }

    float* o = out + ((size_t)b * C * K + k) * SP + p;
#pragma unroll
    for (int c2 = 0; c2 < C; ++c2)
        o[(size_t)c2 * K * SP] = acc[c2 >> 2][c2 & 3];
}

extern "C" void kernel_launch(void* const* d_in, const int* in_sizes, int n_in,
                              void* d_out, int out_size, void* d_ws, size_t ws_size,
                              hipStream_t stream) {
    const float* x = (const float*)d_in[0];
    const float* off = (const float*)d_in[1];
    float* out = (float*)d_out;

    const size_t xt_bytes = (size_t)B * SP * 16 * sizeof(ushort);  // 3.5 MB

    if (ws_size >= xt_bytes) {
        u32* xt = (u32*)d_ws;
        const int n_x = B * SP;
        xpose_bf16_kernel<<<(n_x + 255) / 256, 256, 0, stream>>>(x, xt);
        const long long n_thr = (long long)B * K * SP * 2;   // 5,971,968
        const int grid = (int)(n_thr / 256);                 // 23328, exact
        deform_bf16_v12<<<grid, 256, 0, stream>>>(xt, off, out);
    } else {
        const int n_main = B * K * SP;
        deform_kernel_nat<<<(n_main + 255) / 256, 256, 0, stream>>>(x, off, out);
    }
}

// Round 13
// 110.067 us; speedup vs baseline: 1.1977x; 1.0104x over previous
//
#include <hip/hip_runtime.h>
#include <hip/hip_bf16.h>

typedef float f4 __attribute__((ext_vector_type(4)));
typedef float f2 __attribute__((ext_vector_type(2)));
typedef unsigned int u32;
typedef u32 u4 __attribute__((ext_vector_type(4)));

constexpr int B = 2, C = 16, D = 24, H = 48, W = 48;
constexpr int K = 27;
constexpr int SP = D * H * W;   // 55296 (divisible by 128)
constexpr int HW = H * W;

__device__ inline ushort bf16_bits(float f) {
    __hip_bfloat16 h = __float2bfloat16(f);   // RTN-E
    return __builtin_bit_cast(ushort, h);
}

// x [B,C,S] f32 -> xt [B,S,16ch] bf16 (32 B per spatial point)
__global__ __launch_bounds__(256) void xpose_bf16_kernel(const float* __restrict__ x,
                                                         u32* __restrict__ xt) {
    int t = blockIdx.x * blockDim.x + threadIdx.x;
    if (t >= B * SP) return;
    int s = t % SP, b = t / SP;
    const float* src = x + (size_t)b * C * SP + s;
    u4 pk[2];
#pragma unroll
    for (int m = 0; m < 8; ++m) {
        float lo = src[(size_t)(2 * m) * SP];
        float hi = src[(size_t)(2 * m + 1) * SP];
        pk[m >> 2][m & 3] = (u32)bf16_bits(lo) | ((u32)bf16_bits(hi) << 16);
    }
    u4* dst = reinterpret_cast<u4*>(xt + (size_t)t * 8);
    dst[0] = pk[0];
    dst[1] = pk[1];
}

// R9 mapping (wave = 32 samples x 2 channel-halves), NO LDS, NO barrier:
// direct scalar stores (L2 merges the 128B half-line runs — proven in R1).
__global__ __launch_bounds__(256) void deform_bf16_v13(const u32* __restrict__ xt,
                                                       const float* __restrict__ off,
                                                       float* __restrict__ out) {
    const int tid = blockIdx.x * blockDim.x + threadIdx.x;
    const int l = threadIdx.x & 63;
    const int q = l >> 5;                    // channel half 0/1
    const int c = l & 31;                    // sample-in-wave 0..31
    const int s = (tid >> 6) * 32 + c;       // global sample id
    const int p = s % SP;
    const int bk = s / SP;                   // wave-uniform (SP % 32 == 0)
    const int k = bk % K, b = bk / K;

    // offsets: 1 full-wave + 1 half-wave coalesced load, then shfl broadcast
    const size_t obase = ((size_t)b * (3 * K) + 3 * k) * SP;
    float vdh = __builtin_nontemporal_load(off + obase + (size_t)q * SP + p);
    float vw = 0.0f;
    if (l < 32) vw = __builtin_nontemporal_load(off + obase + (size_t)2 * SP + p);
    float offd = __shfl(vdh, c);
    float offh = __shfl(vdh, c + 32);
    float offw = __shfl(vw, c);

    const int od = p / HW;
    const int rem = p - od * HW;
    const int oh = rem / W, ow = rem - oh * W;
    const int ki = k / 9, kr2 = k - ki * 9;
    const int kj = kr2 / 3, kk = kr2 - kj * 3;

    float pd = (float)(od + ki - 1) + offd;
    float ph = (float)(oh + kj - 1) + offh;
    float pw = (float)(ow + kk - 1) + offw;

    float d0f = floorf(pd), h0f = floorf(ph), w0f = floorf(pw);
    float fd = pd - d0f, fh = ph - h0f, fw = pw - w0f;
    int d0 = (int)d0f, h0 = (int)h0f, w0 = (int)w0f;

    int dc0 = min(max(d0, 0), D - 1) * HW;
    int dc1 = min(max(d0 + 1, 0), D - 1) * HW;
    int hc0 = min(max(h0, 0), H - 1) * W;
    int hc1 = min(max(h0 + 1, 0), H - 1) * W;
    int wc0 = min(max(w0, 0), W - 1);
    int wc1 = min(max(w0 + 1, 0), W - 1);

    const u4* xb = reinterpret_cast<const u4*>(xt) + (size_t)b * SP * 2 + q;

    u4 v[8];
#pragma unroll
    for (int cn = 0; cn < 8; ++cn) {
        int idx = ((cn & 4) ? dc1 : dc0) + ((cn & 2) ? hc1 : hc0) + ((cn & 1) ? wc1 : wc0);
        v[cn] = xb[(size_t)idx * 2];
    }

    bool vd0 = (d0 >= 0) & (d0 < D), vd1 = (d0 + 1 >= 0) & (d0 + 1 < D);
    bool vh0 = (h0 >= 0) & (h0 < H), vh1 = (h0 + 1 >= 0) & (h0 + 1 < H);
    bool vw0 = (w0 >= 0) & (w0 < W), vw1 = (w0 + 1 >= 0) & (w0 + 1 < W);
    float wd0 = 1.0f - fd, wd1 = fd;
    float wh0 = 1.0f - fh, wh1 = fh;
    float ww0 = 1.0f - fw, ww1 = fw;

    float wgt[8];
#pragma unroll
    for (int cn = 0; cn < 8; ++cn) {
        bool valid = ((cn & 4) ? vd1 : vd0) & ((cn & 2) ? vh1 : vh0) & ((cn & 1) ? vw1 : vw0);
        float wv2 = ((cn & 4) ? wd1 : wd0) * ((cn & 2) ? wh1 : wh0) * ((cn & 1) ? ww1 : ww0);
        wgt[cn] = valid ? wv2 : 0.0f;
    }

    f2 acc[4] = {};
#pragma unroll
    for (int cn = 0; cn < 8; ++cn) {
        f2 w2 = {wgt[cn], wgt[cn]};
#pragma unroll
        for (int m = 0; m < 4; ++m) {
            u32 wb = v[cn][m];
            f2 xv = {__builtin_bit_cast(float, wb << 16),
                     __builtin_bit_cast(float, wb & 0xffff0000u)};
            acc[m] += w2 * xv;
        }
    }

    // direct stores: channel ch = 8q + j at spatial p; wave forms two 128B runs
    // per instruction (32 consecutive p x 4B per channel-half) -> L2 merges.
    float* osb = out + (((size_t)b * C + 8 * q) * K + k) * SP + p;
#pragma unroll
    for (int m = 0; m < 4; ++m) {
        osb[(size_t)(2 * m) * K * SP] = acc[m][0];
        osb[(size_t)(2 * m + 1) * K * SP] = acc[m][1];
    }
}

// fallback (no workspace): one thread per sample, gather from native fp32 layout
__global__ __launch_bounds__(256) void deform_kernel_nat(const float* __restrict__ x,
                                                         const float* __restrict__ off,
                                                         float* __restrict__ out) {
    int tid = blockIdx.x * blockDim.x + threadIdx.x;
    if (tid >= B * K * SP) return;
    int p = tid % SP;
    int bk = tid / SP;
    int k = bk % K, b = bk / K;

    const float* ob = off + ((size_t)b * (3 * K) + 3 * k) * SP + p;
    float offd = ob[0];
    float offh = ob[(size_t)SP];
    float offw = ob[(size_t)2 * SP];

    int od = p / HW, rem = p - od * HW;
    int oh = rem / W, ow = rem - oh * W;
    int ki = k / 9, kr = k - ki * 9;
    int kj = kr / 3, kk = kr - kj * 3;

    float pd = (float)(od + ki - 1) + offd;
    float ph = (float)(oh + kj - 1) + offh;
    float pw = (float)(ow + kk - 1) + offw;

    float d0f = floorf(pd), h0f = floorf(ph), w0f = floorf(pw);
    float fd = pd - d0f, fh = ph - h0f, fw = pw - w0f;
    int d0 = (int)d0f, h0 = (int)h0f, w0 = (int)w0f;

    f4 acc[4] = {};
#pragma unroll
    for (int ci = 0; ci < 2; ++ci) {
        int ds = d0 + ci;
        bool vd = (ds >= 0) & (ds < D);
        float wd = ci ? fd : 1.0f - fd;
        int dc = min(max(ds, 0), D - 1);
#pragma unroll
        for (int cj = 0; cj < 2; ++cj) {
            int hs = h0 + cj;
            bool vh = (hs >= 0) & (hs < H);
            float wh = cj ? fh : 1.0f - fh;
            int hc = min(max(hs, 0), H - 1);
#pragma unroll
            for (int ck = 0; ck < 2; ++ck) {
                int ws = w0 + ck;
                bool vw = (ws >= 0) & (ws < W);
                float ww = ck ? fw : 1.0f - fw;
                int wc = min(max(ws, 0), W - 1);
                float wgt = (vd & vh & vw) ? wd * wh * ww : 0.0f;
                int idx = (dc * H + hc) * W + wc;
                const float* src = x + (size_t)b * C * SP + idx;
#pragma unroll
                for (int c2 = 0; c2 < C; ++c2)
                    acc[c2 >> 2][c2 & 3] += wgt * src[(size_t)c2 * SP];
            }
        }
    }

    float* o = out + ((size_t)b * C * K + k) * SP + p;
#pragma unroll
    for (int c2 = 0; c2 < C; ++c2)
        o[(size_t)c2 * K * SP] = acc[c2 >> 2][c2 & 3];
}

extern "C" void kernel_launch(void* const* d_in, const int* in_sizes, int n_in,
                              void* d_out, int out_size, void* d_ws, size_t ws_size,
                              hipStream_t stream) {
    const float* x = (const float*)d_in[0];
    const float* off = (const float*)d_in[1];
    float* out = (float*)d_out;

    const size_t xt_bytes = (size_t)B * SP * 16 * sizeof(ushort);  // 3.5 MB

    if (ws_size >= xt_bytes) {
        u32* xt = (u32*)d_ws;
        const int n_x = B * SP;
        xpose_bf16_kernel<<<(n_x + 255) / 256, 256, 0, stream>>>(x, xt);
        const long long n_thr = (long long)B * K * SP * 2;   // 5,971,968
        const int grid = (int)(n_thr / 256);                 // 23328, exact
        deform_bf16_v13<<<grid, 256, 0, stream>>>(xt, off, out);
    } else {
        const int n_main = B * K * SP;
        deform_kernel_nat<<<(n_main + 255) / 256, 256, 0, stream>>>(x, off, out);
    }
}